// Round 4
// baseline (419.809 us; speedup 1.0000x reference)
//
#include <hip/hip_runtime.h>
#include <hip/hip_cooperative_groups.h>
#include <cstdint>
#include <cstddef>

namespace cg = cooperative_groups;

#define TOPK 9
#define NCLS 80
#define EPSF 1e-9f

typedef float f4v __attribute__((ext_vector_type(4)));

__device__ __forceinline__ float iou_f(float4 b1, float4 b2) {
    float x1 = fmaxf(b1.x, b2.x), y1 = fmaxf(b1.y, b2.y);
    float x2 = fminf(b1.z, b2.z), y2 = fminf(b1.w, b2.w);
    float ov = fmaxf(x2 - x1, 0.f) * fmaxf(y2 - y1, 0.f);
    float a1 = fmaxf(b1.z - b1.x, 0.f) * fmaxf(b1.w - b1.y, 0.f);
    float a2 = fmaxf(b2.z - b2.x, 0.f) * fmaxf(b2.w - b2.y, 0.f);
    return ov / (a1 + a2 - ov + EPSF);
}

// Single cooperative kernel: phase0 zero-mask | sync | phase1 topk+threshold
// +inside+atomicOr | sync | phase2 per-anchor assignment | sync | phase3
// coalesced score fill. Phase bodies are verbatim from the round-3 kernels
// (absmax 0); fusion removes 3 graph nodes + 1 dispatch of replay overhead.
__global__ __launch_bounds__(256, 4) void atss_fused_kernel(
    const float* __restrict__ anchors,     // [A,4]
    const int*   __restrict__ gt_labels,   // [B,M]
    const float* __restrict__ gt_bboxes,   // [B,M,4]
    const float* __restrict__ pad_mask,    // [B,M]
    const float* __restrict__ pred,        // [B,A,4]
    const int*   __restrict__ bg_ptr,
    unsigned long long* __restrict__ pos_mask, // [B,A] ws
    float* __restrict__ piou_ws,           // [B,A] ws
    float* __restrict__ out_labels,        // [B,A]
    float* __restrict__ out_bboxes,        // [B,A,4]
    float* __restrict__ scores,            // [B,A,80]
    int M, int A, int BA, int total4) {
    cg::grid_group grid = cg::this_grid();
    const int tid = blockIdx.x * blockDim.x + threadIdx.x;
    const int nth = gridDim.x * blockDim.x;   // 262144

    // ---- phase 0: zero the positive-mask ----
    for (int i = tid; i < BA; i += nth) pos_mask[i] = 0ull;
    grid.sync();

    // ---- phase 1: per-(b,m) top-9 per level + threshold + inside check ----
    // Anchor centers are a regular grid per level: the top-9 nearest (incl.
    // all tie-competitors at the 9th distance) lie in an 8x8 index window
    // (disk r=2.5s holds >=9 lattice points; window covers Chebyshev +-3s).
    // 64 candidates = 1/lane; rank-select on unique keys (dist_bits<<32|idx)
    // reproduces jax.lax.top_k order + lowest-index tie-break exactly.
    {
        __shared__ unsigned idx27[32];
        __shared__ float    iou27[32];
        const int lane = threadIdx.x & 63;
        const int w = threadIdx.x >> 6;   // wave id 0..3; waves 0-2 = levels

        for (int tt = 0; tt < 2; ++tt) {
            const int bm = blockIdx.x * 2 + tt;   // 2048 tasks
            const int b = bm / M;
            const int m = bm - b * M;

            const float4 g = ((const float4*)gt_bboxes)[bm];
            const float gcx = (g.x + g.z) * 0.5f;
            const float gcy = (g.y + g.w) * 0.5f;

            if (w < 3) {
                const int fsL[3]  = {80, 40, 20};
                const int strL[3] = {8, 16, 32};
                const int stL[3]  = {0, 6400, 8000};
                const int fs = fsL[w];
                const float s = (float)strL[w];
                const int st = stL[w];

                int fx = (int)floorf(gcx / s - 0.5f);
                int fy = (int)floorf(gcy / s - 0.5f);
                int ix0 = min(max(fx - 3, 0), fs - 8);
                int iy0 = min(max(fy - 3, 0), fs - 8);

                const int wx = lane & 7;
                const int wy = lane >> 3;
                int gi = st + (iy0 + wy) * fs + (ix0 + wx);
                float4 a = ((const float4*)anchors)[gi];
                float ddx = (a.x + a.z) * 0.5f - gcx;
                float ddy = (a.y + a.w) * 0.5f - gcy;
                float d = sqrtf(ddx * ddx + ddy * ddy);
                unsigned long long key =
                    ((unsigned long long)__float_as_uint(d) << 32) |
                    (unsigned)gi;

                int rank = 0;
#pragma unroll
                for (int j = 0; j < 64; ++j) {
                    unsigned long long o = __shfl(key, j, 64);
                    rank += (o < key) ? 1 : 0;
                }
                if (rank < TOPK)
                    idx27[w * TOPK + rank] = (unsigned)(key & 0xFFFFFFFFu);
            }
            __syncthreads();

            if (threadIdx.x < 27) {
                float4 ca = ((const float4*)anchors)[idx27[threadIdx.x]];
                iou27[threadIdx.x] = iou_f(g, ca);
            }
            __syncthreads();

            if (threadIdx.x < 27) {
                // thr_v = mean + std(ddof=1); serial order kept identical
                float sum = 0.f;
                for (int k = 0; k < 27; ++k) sum += iou27[k];
                float mean = sum * (1.0f / 27.0f);
                float var = 0.f;
                for (int k = 0; k < 27; ++k) {
                    float dd = iou27[k] - mean;
                    var += dd * dd;
                }
                float thr = mean + sqrtf(var * (1.0f / 26.0f));

                float pad = pad_mask[bm];
                if (pad != 0.f && iou27[threadIdx.x] > thr) {  // strict >
                    unsigned ai = idx27[threadIdx.x];
                    float4 ca = ((const float4*)anchors)[ai];
                    float acx = (ca.x + ca.z) * 0.5f;
                    float acy = (ca.y + ca.w) * 0.5f;
                    float lt = fminf(fminf(acx - g.x, acy - g.y),
                                     fminf(g.z - acx, g.w - acy));
                    if (lt > EPSF) {   // strict >, matches _check_inside
                        atomicOr(&pos_mask[(size_t)b * A + ai], 1ull << m);
                    }
                }
            }
            __syncthreads();   // LDS reused by next task iteration
        }
    }
    grid.sync();

    // ---- phase 2: per-(b,a) assignment ----
    for (int t = tid; t < BA; t += nth) {
        int b = t / A;
        int a = t - b * A;

        unsigned long long mask = pos_mask[t];
        int mps = __popcll(mask);

        int gt = 0;
        if (mps == 1) {
            gt = __builtin_ctzll(mask);
        } else if (mps > 1) {
            // one_hot(argmax_m ious[b,:,a]); strict > keeps first max
            float4 an = ((const float4*)anchors)[a];
            float best = -1.f;
            for (int mm = 0; mm < M; ++mm) {
                float v = iou_f(((const float4*)gt_bboxes)[b * M + mm], an);
                if (v > best) { best = v; gt = mm; }
            }
        }
        // mps==0: argmax of all-zero mask == 0 -> bbox=gt_bboxes[b,0], bg

        float4 gbox = ((const float4*)gt_bboxes)[b * M + gt];
        int label = (mps > 0) ? gt_labels[b * M + gt] : bg_ptr[0];

        out_labels[t] = (float)label;
        ((float4*)out_bboxes)[t] = gbox;

        float pi = 0.f;
        if (mps > 0) {
            float4 p = ((const float4*)pred)[t];
            pi = iou_f(gbox, p);   // pious.max over m == iou with assigned gt
        }
        piou_ws[t] = pi;
    }
    grid.sync();

    // ---- phase 3: score fill (one-hot * piou), float4-coalesced NT ----
    for (int t = tid; t < total4; t += nth) {
        int anchor = t / (NCLS / 4);
        int c0 = (t - anchor * (NCLS / 4)) * 4;
        int label = (int)out_labels[anchor];   // bg=80 never matches
        float pi = piou_ws[anchor];
        f4v v;
        v.x = (c0 + 0 == label) ? pi : 0.f;
        v.y = (c0 + 1 == label) ? pi : 0.f;
        v.z = (c0 + 2 == label) ? pi : 0.f;
        v.w = (c0 + 3 == label) ? pi : 0.f;
        __builtin_nontemporal_store(v, (f4v*)scores + t);
    }
}

extern "C" void kernel_launch(void* const* d_in, const int* in_sizes, int n_in,
                              void* d_out, int out_size, void* d_ws, size_t ws_size,
                              hipStream_t stream) {
    const float* anchors   = (const float*)d_in[0];
    const int*   gt_labels = (const int*)d_in[1];
    const float* gt_bboxes = (const float*)d_in[2];
    const float* pad_mask  = (const float*)d_in[3];
    const float* pred      = (const float*)d_in[4];
    const int*   bg_ptr    = (const int*)d_in[5];

    int A  = in_sizes[0] / 4;   // 8400
    int BM = in_sizes[1];       // 2048
    int M  = 64;
    int B  = BM / M;            // 32
    int BA = B * A;             // 268800
    int total4 = BA * (NCLS / 4);

    float* out_labels = (float*)d_out;
    float* out_bboxes = out_labels + (size_t)BA;
    float* scores     = out_bboxes + (size_t)BA * 4;

    unsigned long long* pos_mask = (unsigned long long*)d_ws;
    float* piou_ws = (float*)((char*)d_ws + (size_t)BA * sizeof(unsigned long long));

    void* args[] = {
        (void*)&anchors, (void*)&gt_labels, (void*)&gt_bboxes,
        (void*)&pad_mask, (void*)&pred, (void*)&bg_ptr,
        (void*)&pos_mask, (void*)&piou_ws,
        (void*)&out_labels, (void*)&out_bboxes, (void*)&scores,
        (void*)&M, (void*)&A, (void*)&BA, (void*)&total4};

    // 1024 blocks x 256 thr = 4 blocks/CU (16 waves/CU) — co-resident per
    // __launch_bounds__(256,4); phase1 maps 2 (b,m) tasks per block.
    hipLaunchCooperativeKernel((void*)atss_fused_kernel,
                               dim3(1024), dim3(256), args, 0, stream);
}

// Round 5
// 138.215 us; speedup vs baseline: 3.0374x; 3.0374x over previous
//
#include <hip/hip_runtime.h>
#include <cstdint>
#include <cstddef>

#define TOPK 9
#define NCLS 80
#define EPSF 1e-9f
#define CHUNK 525   // 8400 = 16 * 525, exact

typedef float f4v __attribute__((ext_vector_type(4)));

__device__ __forceinline__ float iou_f(float4 b1, float4 b2) {
    float x1 = fmaxf(b1.x, b2.x), y1 = fmaxf(b1.y, b2.y);
    float x2 = fminf(b1.z, b2.z), y2 = fminf(b1.w, b2.w);
    float ov = fmaxf(x2 - x1, 0.f) * fmaxf(y2 - y1, 0.f);
    float a1 = fmaxf(b1.z - b1.x, 0.f) * fmaxf(b1.w - b1.y, 0.f);
    float a2 = fmaxf(b2.z - b2.x, 0.f) * fmaxf(b2.w - b2.y, 0.f);
    return ov / (a1 + a2 - ov + EPSF);
}

// -------- kernel A: per-(b,m) top-9/level + threshold + inside check --------
// One block (3 waves) per (b,m); wave w = pyramid level w. Grid-window
// argument (8x8 window covers all top-9 + tie-competitors) and rank-select
// are identical to round 3 (absmax 0). NEW epilogue: instead of atomicOr
// into a pre-zeroed global mask, wave 0 ballot-packs the accepted anchors
// (same accept condition) into a compact per-(b,m) list — removes the
// zero-mask kernel node and the 2.15 MB mask round-trip.
__global__ __launch_bounds__(192) void atss_topk_kernel(
    const float* __restrict__ anchors,     // [A,4]
    const float* __restrict__ gt_bboxes,   // [B,M,4]
    const float* __restrict__ pad_mask,    // [B,M]
    int* __restrict__ acc_cnt,             // [B*M]
    int* __restrict__ acc_list,            // [B*M, 27]
    int M, int A) {
    const int bm = blockIdx.x;
    const int lane = threadIdx.x & 63;
    const int w = threadIdx.x >> 6;      // level = wave id (0..2)

    const float4 g = ((const float4*)gt_bboxes)[bm];
    const float gcx = (g.x + g.z) * 0.5f;
    const float gcy = (g.y + g.w) * 0.5f;

    __shared__ unsigned idx27[32];
    __shared__ float    iou27[32];

    const int fsL[3]  = {80, 40, 20};
    const int strL[3] = {8, 16, 32};
    const int stL[3]  = {0, 6400, 8000};

    if (w < 3) {
        const int fs = fsL[w];
        const float s = (float)strL[w];
        const int st = stL[w];

        int fx = (int)floorf(gcx / s - 0.5f);
        int fy = (int)floorf(gcy / s - 0.5f);
        int ix0 = min(max(fx - 3, 0), fs - 8);
        int iy0 = min(max(fy - 3, 0), fs - 8);

        const int wx = lane & 7;
        const int wy = lane >> 3;
        int gi = st + (iy0 + wy) * fs + (ix0 + wx);
        float4 a = ((const float4*)anchors)[gi];
        float ddx = (a.x + a.z) * 0.5f - gcx;
        float ddy = (a.y + a.w) * 0.5f - gcy;
        float d = sqrtf(ddx * ddx + ddy * ddy);
        unsigned long long key =
            ((unsigned long long)__float_as_uint(d) << 32) | (unsigned)gi;

        int rank = 0;
#pragma unroll
        for (int j = 0; j < 64; ++j) {
            unsigned long long o = __shfl(key, j, 64);
            rank += (o < key) ? 1 : 0;
        }
        if (rank < TOPK)
            idx27[w * TOPK + rank] = (unsigned)(key & 0xFFFFFFFFu);
    }
    __syncthreads();

    if (threadIdx.x < 27) {
        float4 ca = ((const float4*)anchors)[idx27[threadIdx.x]];
        iou27[threadIdx.x] = iou_f(g, ca);
    }
    __syncthreads();

    bool accept = false;
    unsigned ai = 0;
    if (threadIdx.x < 27) {
        // thr_v = mean + std(ddof=1); serial order identical to rounds 1-3
        float sum = 0.f;
        for (int k = 0; k < 27; ++k) sum += iou27[k];
        float mean = sum * (1.0f / 27.0f);
        float var = 0.f;
        for (int k = 0; k < 27; ++k) {
            float dd = iou27[k] - mean;
            var += dd * dd;
        }
        float thr = mean + sqrtf(var * (1.0f / 26.0f));

        float pad = pad_mask[bm];
        if (pad != 0.f && iou27[threadIdx.x] > thr) {   // strict >, as ref
            ai = idx27[threadIdx.x];
            float4 ca = ((const float4*)anchors)[ai];
            float acx = (ca.x + ca.z) * 0.5f;
            float acy = (ca.y + ca.w) * 0.5f;
            float lt = fminf(fminf(acx - g.x, acy - g.y),
                             fminf(g.z - acx, g.w - acy));
            accept = (lt > EPSF);   // strict >, matches _check_inside
        }
    }
    if (threadIdx.x < 64) {   // wave 0 fully active for the ballot
        unsigned long long bal = __ballot(accept);
        if (accept) {
            int pos = __popcll(bal & ((1ull << threadIdx.x) - 1ull));
            acc_list[bm * 27 + pos] = (int)ai;
        }
        if (threadIdx.x == 0) acc_cnt[bm] = __popcll(bal);
    }
}

// -------- kernel B: fused assignment + score fill --------
// One block per (b, 525-anchor chunk). Rebuilds the per-anchor gt-mask in
// LDS from the compact lists (32-bit LDS atomics), runs the round-3
// assignment logic per anchor, stages label/piou in LDS, then writes the
// [chunk,80] score slab coalesced with NT float4 stores. Removes the
// separate scores kernel + piou/label global round-trip.
__global__ __launch_bounds__(256) void atss_assign_scores_kernel(
    const float* __restrict__ anchors,    // [A,4]
    const int*   __restrict__ gt_labels,  // [B,M]
    const float* __restrict__ gt_bboxes,  // [B,M,4]
    const float* __restrict__ pred,       // [B,A,4]
    const int*   __restrict__ bg_ptr,
    const int*   __restrict__ acc_cnt,    // [B*M]
    const int*   __restrict__ acc_list,   // [B*M, 27]
    float* __restrict__ out_labels,       // [B,A]
    float* __restrict__ out_bboxes,       // [B,A,4]
    float* __restrict__ scores,           // [B,A,80]
    int M, int A) {
    __shared__ unsigned mlo[CHUNK];
    __shared__ unsigned mhi[CHUNK];
    __shared__ float    slab[CHUNK];
    __shared__ float    spio[CHUNK];

    const int b = blockIdx.y;
    const int a0 = blockIdx.x * CHUNK;
    const int tid = threadIdx.x;

    for (int i = tid; i < CHUNK; i += 256) { mlo[i] = 0u; mhi[i] = 0u; }
    __syncthreads();

    // scatter accepted anchors of this b into the LDS mask
    {
        const int m = tid >> 2;          // 4 threads per m
        const int ks = tid & 3;
        const int bm = b * M + m;
        const int cnt = acc_cnt[bm];
        for (int k = ks; k < cnt; k += 4) {
            int aidx = acc_list[bm * 27 + k];
            unsigned loc = (unsigned)(aidx - a0);
            if (loc < (unsigned)CHUNK) {
                if (m < 32) atomicOr(&mlo[loc], 1u << m);
                else        atomicOr(&mhi[loc], 1u << (m - 32));
            }
        }
    }
    __syncthreads();

    const int bg = bg_ptr[0];
    for (int loc = tid; loc < CHUNK; loc += 256) {
        const int a = a0 + loc;
        unsigned long long mask =
            ((unsigned long long)mhi[loc] << 32) | (unsigned long long)mlo[loc];
        int mps = __popcll(mask);

        int gt = 0;
        if (mps == 1) {
            gt = __builtin_ctzll(mask);
        } else if (mps > 1) {
            // one_hot(argmax_m ious[b,:,a]); strict > keeps first max
            float4 an = ((const float4*)anchors)[a];
            float best = -1.f;
            for (int mm = 0; mm < M; ++mm) {
                float v = iou_f(((const float4*)gt_bboxes)[b * M + mm], an);
                if (v > best) { best = v; gt = mm; }
            }
        }
        // mps==0: argmax of all-zero mask == 0 -> bbox=gt_bboxes[b,0], bg

        float4 gbox = ((const float4*)gt_bboxes)[b * M + gt];
        int label = (mps > 0) ? gt_labels[b * M + gt] : bg;

        size_t t = (size_t)b * A + a;
        __builtin_nontemporal_store((float)label, out_labels + t);
        f4v gb = {gbox.x, gbox.y, gbox.z, gbox.w};
        __builtin_nontemporal_store(gb, (f4v*)out_bboxes + t);

        float pi = 0.f;
        if (mps > 0) {
            float4 p = ((const float4*)pred)[t];
            pi = iou_f(gbox, p);   // pious.max over m == iou w/ assigned gt
        }
        slab[loc] = (float)label;
        spio[loc] = pi;
    }
    __syncthreads();

    // coalesced NT score writes: [CHUNK, 80] slab, 20 float4 per anchor
    const int n4 = CHUNK * (NCLS / 4);
    const size_t base4 = ((size_t)b * A + a0) * (NCLS / 4);
    for (int idx = tid; idx < n4; idx += 256) {
        int loc = idx / (NCLS / 4);
        int c0 = (idx - loc * (NCLS / 4)) * 4;
        int label = (int)slab[loc];    // bg=80 never matches c in [0,80)
        float pi = spio[loc];
        f4v v;
        v.x = (c0 + 0 == label) ? pi : 0.f;
        v.y = (c0 + 1 == label) ? pi : 0.f;
        v.z = (c0 + 2 == label) ? pi : 0.f;
        v.w = (c0 + 3 == label) ? pi : 0.f;
        __builtin_nontemporal_store(v, (f4v*)scores + base4 + idx);
    }
}

extern "C" void kernel_launch(void* const* d_in, const int* in_sizes, int n_in,
                              void* d_out, int out_size, void* d_ws, size_t ws_size,
                              hipStream_t stream) {
    const float* anchors   = (const float*)d_in[0];
    const int*   gt_labels = (const int*)d_in[1];
    const float* gt_bboxes = (const float*)d_in[2];
    const float* pad_mask  = (const float*)d_in[3];
    const float* pred      = (const float*)d_in[4];
    const int*   bg_ptr    = (const int*)d_in[5];

    const int A  = in_sizes[0] / 4;   // 8400
    const int BM = in_sizes[1];       // 2048
    const int M  = 64;
    const int B  = BM / M;            // 32
    const int BA = B * A;             // 268800

    float* out_labels = (float*)d_out;
    float* out_bboxes = out_labels + (size_t)BA;
    float* scores     = out_bboxes + (size_t)BA * 4;

    int* acc_cnt  = (int*)d_ws;                   // [BM]
    int* acc_list = acc_cnt + BM;                 // [BM*27]
    // acc_cnt fully rewritten each call; acc_list read only up to cnt —
    // stale 0xAA poison beyond cnt is never touched.

    atss_topk_kernel<<<BM, 192, 0, stream>>>(anchors, gt_bboxes, pad_mask,
                                             acc_cnt, acc_list, M, A);
    atss_assign_scores_kernel<<<dim3(A / CHUNK, B), 256, 0, stream>>>(
        anchors, gt_labels, gt_bboxes, pred, bg_ptr, acc_cnt, acc_list,
        out_labels, out_bboxes, scores, M, A);
}